// Round 1
// baseline (1429.664 us; speedup 1.0000x reference)
//
#include <hip/hip_runtime.h>

#define NN 8192
#define DD 256
#define ALPHA 50.0f
#define BETA 1.0f

typedef __attribute__((ext_vector_type(8))) short short8;
typedef __attribute__((ext_vector_type(4))) float f32x4;

static __device__ __forceinline__ ushort f2bf(float f) {
    union { float f; unsigned u; } v; v.f = f;
    unsigned u = v.u;
    return (ushort)((u + 0x7fffu + ((u >> 16) & 1u)) >> 16);
}

// --- W f32 -> bf16, once ---
__global__ void k_wconv(const float* __restrict__ W, ushort* __restrict__ Wb) {
    int i = blockIdx.x * 256 + threadIdx.x;
    Wb[i] = f2bf(W[i]);
}

// --- H f32 -> Hv bf16 (row-major) and Hvt bf16 (transposed [D][N]) ---
// 64x64 tile per block, 256 threads
__global__ __launch_bounds__(256) void k_convert(const float* __restrict__ H,
                                                 ushort* __restrict__ Hv,
                                                 ushort* __restrict__ Hvt) {
    __shared__ ushort T[64][72];  // padded
    int tile = blockIdx.x;                  // 128 row-tiles * 4 col-tiles
    int r0 = (tile >> 2) * 64;
    int c0 = (tile & 3) * 64;
    int tid = threadIdx.x;
    int tr = tid >> 4;            // 0..15
    int tc = (tid & 15) * 4;      // 0..60
    for (int i = 0; i < 4; ++i) {
        int r = tr + i * 16;
        float4 v = *reinterpret_cast<const float4*>(H + (size_t)(r0 + r) * DD + c0 + tc);
        ushort4 o;
        o.x = f2bf(v.x); o.y = f2bf(v.y); o.z = f2bf(v.z); o.w = f2bf(v.w);
        *reinterpret_cast<ushort4*>(Hv + (size_t)(r0 + r) * DD + c0 + tc) = o;
        T[tc + 0][r] = o.x; T[tc + 1][r] = o.y; T[tc + 2][r] = o.z; T[tc + 3][r] = o.w;
    }
    __syncthreads();
    for (int i = 0; i < 4; ++i) {
        int c = tr + i * 16;      // local col -> global row of Hvt
        ushort4 o;
        o.x = T[c][tc + 0]; o.y = T[c][tc + 1]; o.z = T[c][tc + 2]; o.w = T[c][tc + 3];
        *reinterpret_cast<ushort4*>(Hvt + (size_t)(c0 + c) * NN + r0 + tc) = o;
    }
}

// --- Hp = bf16(Hv @ W^T + b) via MFMA ---
// grid = N/64 blocks, 4 waves, each wave 16 rows x 256 cols
__global__ __launch_bounds__(256) void k_proj(const ushort* __restrict__ Hv,
                                              const ushort* __restrict__ Wb,
                                              const float* __restrict__ b,
                                              ushort* __restrict__ Hp) {
    int w = threadIdx.x >> 6;
    int lane = threadIdx.x & 63;
    int row0 = blockIdx.x * 64 + w * 16;
    int lr = lane & 15;
    int lk = lane >> 4;
    short8 af[8];
    for (int kk = 0; kk < 8; ++kk)
        af[kk] = *reinterpret_cast<const short8*>(Hv + (size_t)(row0 + lr) * DD + kk * 32 + lk * 8);
    for (int t = 0; t < 16; ++t) {
        f32x4 acc = {0.f, 0.f, 0.f, 0.f};
        int col = t * 16 + lr;
        for (int kk = 0; kk < 8; ++kk) {
            short8 bf = *reinterpret_cast<const short8*>(Wb + (size_t)col * DD + kk * 32 + lk * 8);
            acc = __builtin_amdgcn_mfma_f32_16x16x32_bf16(af[kk], bf, acc, 0, 0, 0);
        }
        float bias = b[col];
        for (int j = 0; j < 4; ++j) {
            int row = row0 + lk * 4 + j;
            Hp[(size_t)row * DD + col] = f2bf(acc[j] + bias);
        }
    }
}

// --- fused masked flash attention + CRF update ---
// grid = N/16 blocks, 256 threads (4 waves). Each block: 16 query rows.
// Wave w covers keys [w*2048, (w+1)*2048). Block-level flash merge at end.
// Hout = (ALPHA*Q + (lamb@H)) / (ALPHA+BETA)
__global__ __launch_bounds__(256) void k_attn(const ushort* __restrict__ Hp,
                                              const ushort* __restrict__ Hvt,
                                              const float* __restrict__ sim,
                                              const float* __restrict__ Qo,
                                              float* __restrict__ Hout) {
    __shared__ ushort Plds[4][16][32];
    __shared__ float Osum[16][256];
    __shared__ float Msh[4][16];
    __shared__ float Lsh[4][16];
    __shared__ float Lrow[16];

    int w = threadIdx.x >> 6;
    int lane = threadIdx.x & 63;
    int q0 = blockIdx.x * 16;
    int lr = lane & 15;
    int lk = lane >> 4;

    // zero merge buffer (used only after main loop; ordered by later barriers)
    for (int i = threadIdx.x; i < 16 * 256; i += 256) (&Osum[0][0])[i] = 0.f;

    short8 qf[8];
    for (int kk = 0; kk < 8; ++kk)
        qf[kk] = *reinterpret_cast<const short8*>(Hp + (size_t)(q0 + lr) * DD + kk * 32 + lk * 8);

    f32x4 o[16];
    for (int t = 0; t < 16; ++t) o[t] = {0.f, 0.f, 0.f, 0.f};
    float m[4] = {-1e30f, -1e30f, -1e30f, -1e30f};
    float l[4] = {0.f, 0.f, 0.f, 0.f};

    const int kstart = w * (NN / 4);
    for (int step = 0; step < (NN / 4) / 32; ++step) {
        int kb = kstart + step * 32;
        // S = Qp * Kp^T for 16 q-rows x 32 keys
        f32x4 s0 = {0.f, 0.f, 0.f, 0.f}, s1 = {0.f, 0.f, 0.f, 0.f};
        for (int kk = 0; kk < 8; ++kk) {
            short8 k0 = *reinterpret_cast<const short8*>(Hp + (size_t)(kb + lr) * DD + kk * 32 + lk * 8);
            short8 k1 = *reinterpret_cast<const short8*>(Hp + (size_t)(kb + 16 + lr) * DD + kk * 32 + lk * 8);
            s0 = __builtin_amdgcn_mfma_f32_16x16x32_bf16(qf[kk], k0, s0, 0, 0, 0);
            s1 = __builtin_amdgcn_mfma_f32_16x16x32_bf16(qf[kk], k1, s1, 0, 0, 0);
        }
        // mask + chunk row-max (row q = q0 + lk*4 + j lives in 16 lanes sharing lk, across lr)
        float cm[4];
        for (int j = 0; j < 4; ++j) {
            size_t row = (size_t)(q0 + lk * 4 + j);
            float m0 = sim[row * NN + kb + lr];
            float m1 = sim[row * NN + kb + 16 + lr];
            float a0 = (m0 == 0.f) ? -1e30f : s0[j];
            float a1 = (m1 == 0.f) ? -1e30f : s1[j];
            s0[j] = a0; s1[j] = a1;
            float mx = fmaxf(a0, a1);
            mx = fmaxf(mx, __shfl_xor(mx, 1));
            mx = fmaxf(mx, __shfl_xor(mx, 2));
            mx = fmaxf(mx, __shfl_xor(mx, 4));
            mx = fmaxf(mx, __shfl_xor(mx, 8));
            cm[j] = mx;
        }
        float p0[4], p1[4];
        for (int j = 0; j < 4; ++j) {
            float mn = fmaxf(m[j], cm[j]);
            float scale = __expf(m[j] - mn);          // exp(-1e30)=0; both -1e30 -> 1
            float a0 = s0[j], a1 = s1[j];
            float e0 = (a0 < -1e29f) ? 0.f : __expf(a0 - mn);
            float e1 = (a1 < -1e29f) ? 0.f : __expf(a1 - mn);
            float ps = e0 + e1;
            ps += __shfl_xor(ps, 1);
            ps += __shfl_xor(ps, 2);
            ps += __shfl_xor(ps, 4);
            ps += __shfl_xor(ps, 8);
            l[j] = l[j] * scale + ps;
            m[j] = mn;
            p0[j] = e0; p1[j] = e1;
            for (int t = 0; t < 16; ++t) o[t][j] *= scale;
        }
        // P (D-layout) -> LDS row-major [16 q][32 k]
        for (int j = 0; j < 4; ++j) {
            Plds[w][lk * 4 + j][lr]      = f2bf(p0[j]);
            Plds[w][lk * 4 + j][16 + lr] = f2bf(p1[j]);
        }
        __syncthreads();
        short8 pa = *reinterpret_cast<const short8*>(&Plds[w][lr][lk * 8]);
        // O += P @ V  (V rows = H rows, via transposed Hvt for contiguous frags)
        for (int t = 0; t < 16; ++t) {
            short8 vf = *reinterpret_cast<const short8*>(Hvt + (size_t)(t * 16 + lr) * NN + kb + lk * 8);
            o[t] = __builtin_amdgcn_mfma_f32_16x16x32_bf16(pa, vf, o[t], 0, 0, 0);
        }
    }

    // ---- block-level flash merge of 4 key-split partials ----
    if (lr == 0) {
        for (int j = 0; j < 4; ++j) { Msh[w][lk * 4 + j] = m[j]; Lsh[w][lk * 4 + j] = l[j]; }
    }
    __syncthreads();
    float fac[4];
    for (int j = 0; j < 4; ++j) {
        int q = lk * 4 + j;
        float M = fmaxf(fmaxf(Msh[0][q], Msh[1][q]), fmaxf(Msh[2][q], Msh[3][q]));
        fac[j] = __expf(m[j] - M);
    }
    if (threadIdx.x < 16) {
        int q = threadIdx.x;
        float M = fmaxf(fmaxf(Msh[0][q], Msh[1][q]), fmaxf(Msh[2][q], Msh[3][q]));
        float L = 0.f;
        for (int ww = 0; ww < 4; ++ww) L += __expf(Msh[ww][q] - M) * Lsh[ww][q];
        Lrow[q] = L;
    }
    for (int ww = 0; ww < 4; ++ww) {
        if (w == ww) {
            for (int t = 0; t < 16; ++t)
                for (int j = 0; j < 4; ++j)
                    Osum[lk * 4 + j][t * 16 + lr] += fac[j] * o[t][j];
        }
        __syncthreads();
    }
    // final write: H = (ALPHA*Q + Osum/L) / (ALPHA+BETA)
    for (int rep = 0; rep < 16; ++rep) {
        int e = rep * 256 + threadIdx.x;
        int r = e >> 8;
        int c = e & 255;
        float val = (ALPHA * Qo[(size_t)(q0 + r) * DD + c] + Osum[r][c] / Lrow[r]) * (1.0f / (ALPHA + BETA));
        Hout[(size_t)(q0 + r) * DD + c] = val;
    }
}

extern "C" void kernel_launch(void* const* d_in, const int* in_sizes, int n_in,
                              void* d_out, int out_size, void* d_ws, size_t ws_size,
                              hipStream_t stream) {
    const float* Q   = (const float*)d_in[0];
    const float* sim = (const float*)d_in[1];
    const float* W   = (const float*)d_in[2];
    const float* b   = (const float*)d_in[3];
    float* out = (float*)d_out;

    char* ws = (char*)d_ws;
    size_t off = 0;
    ushort* Hv  = (ushort*)(ws + off); off += (size_t)NN * DD * 2;
    ushort* Hvt = (ushort*)(ws + off); off += (size_t)NN * DD * 2;
    ushort* Hp  = (ushort*)(ws + off); off += (size_t)NN * DD * 2;
    ushort* Wb  = (ushort*)(ws + off); off += (size_t)DD * DD * 2;
    float*  H1  = (float*)(ws + off);  off += (size_t)NN * DD * 4;

    k_wconv<<<DD * DD / 256, 256, 0, stream>>>(W, Wb);

    const float* Hcur = Q;
    for (int it = 0; it < 2; ++it) {
        float* Hnext = (it == 0) ? H1 : out;
        k_convert<<<(NN / 64) * (DD / 64), 256, 0, stream>>>(Hcur, Hv, Hvt);
        k_proj<<<NN / 64, 256, 0, stream>>>(Hv, Wb, b, Hp);
        k_attn<<<NN / 16, 256, 0, stream>>>(Hp, Hvt, sim, Q, Hnext);
        Hcur = Hnext;
    }
}

// Round 4
// 1058.104 us; speedup vs baseline: 1.3512x; 1.3512x over previous
//
#include <hip/hip_runtime.h>

#define NN 8192
#define DD 256
#define ALPHA 50.0f
#define BETA 1.0f
#define THR 8.0f

typedef __attribute__((ext_vector_type(8))) short short8;
typedef __attribute__((ext_vector_type(4))) float f32x4;

static __device__ __forceinline__ ushort f2bf(float f) {
    union { float f; unsigned u; } v; v.f = f;
    unsigned u = v.u;
    return (ushort)((u + 0x7fffu + ((u >> 16) & 1u)) >> 16);
}

// --- W f32 -> bf16, once ---
__global__ void k_wconv(const float* __restrict__ W, ushort* __restrict__ Wb) {
    int i = blockIdx.x * 256 + threadIdx.x;
    Wb[i] = f2bf(W[i]);
}

// --- bitpack mask: bits[row][col/32], bit c = (sim[row][col] != 0) ---
__global__ __launch_bounds__(256) void k_pack(const float* __restrict__ sim,
                                              unsigned* __restrict__ bits) {
    int row = blockIdx.x;
    int w = threadIdx.x >> 6;
    int lane = threadIdx.x & 63;
    for (int p = 0; p < 32; ++p) {
        int col = p * 256 + w * 64 + lane;
        float v = sim[(size_t)row * NN + col];
        unsigned long long b = __ballot(v != 0.0f);
        if (lane == 0) {
            bits[row * (NN / 32) + p * 8 + w * 2]     = (unsigned)b;
            bits[row * (NN / 32) + p * 8 + w * 2 + 1] = (unsigned)(b >> 32);
        }
    }
}

// --- H f32 -> Hv bf16 (row-major) and Hvt bf16 (transposed [D][N]) ---
__global__ __launch_bounds__(256) void k_convert(const float* __restrict__ H,
                                                 ushort* __restrict__ Hv,
                                                 ushort* __restrict__ Hvt) {
    __shared__ ushort T[64][72];  // padded
    int tile = blockIdx.x;                  // 128 row-tiles * 4 col-tiles
    int r0 = (tile >> 2) * 64;
    int c0 = (tile & 3) * 64;
    int tid = threadIdx.x;
    int tr = tid >> 4;            // 0..15
    int tc = (tid & 15) * 4;      // 0..60
    for (int i = 0; i < 4; ++i) {
        int r = tr + i * 16;
        float4 v = *reinterpret_cast<const float4*>(H + (size_t)(r0 + r) * DD + c0 + tc);
        ushort4 o;
        o.x = f2bf(v.x); o.y = f2bf(v.y); o.z = f2bf(v.z); o.w = f2bf(v.w);
        *reinterpret_cast<ushort4*>(Hv + (size_t)(r0 + r) * DD + c0 + tc) = o;
        T[tc + 0][r] = o.x; T[tc + 1][r] = o.y; T[tc + 2][r] = o.z; T[tc + 3][r] = o.w;
    }
    __syncthreads();
    for (int i = 0; i < 4; ++i) {
        int c = tr + i * 16;      // local col -> global row of Hvt
        ushort4 o;
        o.x = T[c][tc + 0]; o.y = T[c][tc + 1]; o.z = T[c][tc + 2]; o.w = T[c][tc + 3];
        *reinterpret_cast<ushort4*>(Hvt + (size_t)(c0 + c) * NN + r0 + tc) = o;
    }
}

// --- Hp = bf16(Hv @ W^T + b) via MFMA ---
__global__ __launch_bounds__(256) void k_proj(const ushort* __restrict__ Hv,
                                              const ushort* __restrict__ Wb,
                                              const float* __restrict__ b,
                                              ushort* __restrict__ Hp) {
    int w = threadIdx.x >> 6;
    int lane = threadIdx.x & 63;
    int row0 = blockIdx.x * 64 + w * 16;
    int lr = lane & 15;
    int lk = lane >> 4;
    short8 af[8];
    for (int kk = 0; kk < 8; ++kk)
        af[kk] = *reinterpret_cast<const short8*>(Hv + (size_t)(row0 + lr) * DD + kk * 32 + lk * 8);
    for (int t = 0; t < 16; ++t) {
        f32x4 acc = {0.f, 0.f, 0.f, 0.f};
        int col = t * 16 + lr;
        for (int kk = 0; kk < 8; ++kk) {
            short8 bf = *reinterpret_cast<const short8*>(Wb + (size_t)col * DD + kk * 32 + lk * 8);
            acc = __builtin_amdgcn_mfma_f32_16x16x32_bf16(af[kk], bf, acc, 0, 0, 0);
        }
        float bias = b[col];
        for (int j = 0; j < 4; ++j) {
            int row = row0 + lk * 4 + j;
            Hp[(size_t)row * DD + col] = f2bf(acc[j] + bias);
        }
    }
}

// --- fused masked flash attention + CRF update ---
// grid = N/16 blocks, 4 waves; wave w covers keys [w*2048,(w+1)*2048).
// Bitpacked mask; defer-max rescale; l folded into PV via ones-column.
__global__ __launch_bounds__(256) void k_attn(const ushort* __restrict__ Hp,
                                              const ushort* __restrict__ Hvt,
                                              const unsigned* __restrict__ bits,
                                              const float* __restrict__ Qo,
                                              ushort* __restrict__ HvOut,
                                              ushort* __restrict__ HvtOut,
                                              float* __restrict__ Fout) {
    __shared__ ushort Plds[4][16][32];
    __shared__ float Osum[16][257];   // 257: conflict-free transposed read
    __shared__ float Msh[4][16];
    __shared__ float Lsh[4][16];
    __shared__ float Lrow[16];

    const int w = threadIdx.x >> 6;
    const int lane = threadIdx.x & 63;
    const int q0 = blockIdx.x * 16;
    const int lr = lane & 15;
    const int lk = lane >> 4;

    for (int i = threadIdx.x; i < 16 * 257; i += 256) (&Osum[0][0])[i] = 0.f;

    short8 qf[8];
#pragma unroll
    for (int kk = 0; kk < 8; ++kk)
        qf[kk] = *reinterpret_cast<const short8*>(Hp + (size_t)(q0 + lr) * DD + kk * 32 + lk * 8);

    f32x4 o[17];
#pragma unroll
    for (int t = 0; t < 17; ++t) o[t] = {0.f, 0.f, 0.f, 0.f};
    float m[4] = {-1e30f, -1e30f, -1e30f, -1e30f};

    short8 ones;
#pragma unroll
    for (int e = 0; e < 8; ++e) ones[e] = (short)0x3f80;  // bf16 1.0

    const int rowbase = (q0 + lk * 4) * (NN / 32);
    const int kstart = w * (NN / 4);
    for (int step = 0; step < (NN / 4) / 32; ++step) {
        const int kb = kstart + step * 32;
        const int wi = kb >> 5;
        // broadcast mask words for this step's 4 q-rows (issued early)
        unsigned mwj[4];
#pragma unroll
        for (int j = 0; j < 4; ++j) mwj[j] = bits[rowbase + j * (NN / 32) + wi];

        f32x4 s0 = {0.f, 0.f, 0.f, 0.f}, s1 = {0.f, 0.f, 0.f, 0.f};
#pragma unroll
        for (int kk = 0; kk < 8; ++kk) {
            short8 k0 = *reinterpret_cast<const short8*>(Hp + (size_t)(kb + lr) * DD + kk * 32 + lk * 8);
            short8 k1 = *reinterpret_cast<const short8*>(Hp + (size_t)(kb + 16 + lr) * DD + kk * 32 + lk * 8);
            s0 = __builtin_amdgcn_mfma_f32_16x16x32_bf16(qf[kk], k0, s0, 0, 0, 0);
            s1 = __builtin_amdgcn_mfma_f32_16x16x32_bf16(qf[kk], k1, s1, 0, 0, 0);
        }
        // mask + defer-max check (no shuffles on light path)
        float c = -1e30f;
#pragma unroll
        for (int j = 0; j < 4; ++j) {
            float a0 = ((mwj[j] >> lr) & 1u) ? s0[j] : -1e30f;
            float a1 = ((mwj[j] >> (lr + 16)) & 1u) ? s1[j] : -1e30f;
            s0[j] = a0; s1[j] = a1;
            c = fmaxf(c, fmaxf(a0, a1) - m[j]);
        }
        if (__any(c > THR)) {   // rare: new-max rescale
#pragma unroll
            for (int j = 0; j < 4; ++j) {
                float mx = fmaxf(s0[j], s1[j]);
                mx = fmaxf(mx, __shfl_xor(mx, 1));
                mx = fmaxf(mx, __shfl_xor(mx, 2));
                mx = fmaxf(mx, __shfl_xor(mx, 4));
                mx = fmaxf(mx, __shfl_xor(mx, 8));
                float mn = fmaxf(m[j], mx);
                float scale = __expf(m[j] - mn);
                m[j] = mn;
#pragma unroll
                for (int t = 0; t < 17; ++t) o[t][j] *= scale;
            }
        }
        // P -> LDS (wave-private tile; masked entries underflow to 0,
        // all-masked-so-far junk (exp(0)=1) is wiped by scale=0 on first real max)
#pragma unroll
        for (int j = 0; j < 4; ++j) {
            Plds[w][lk * 4 + j][lr]      = f2bf(__expf(s0[j] - m[j]));
            Plds[w][lk * 4 + j][16 + lr] = f2bf(__expf(s1[j] - m[j]));
        }
        asm volatile("s_waitcnt lgkmcnt(0)" ::: "memory");
        __builtin_amdgcn_sched_barrier(0);
        short8 pa = *reinterpret_cast<const short8*>(&Plds[w][lr][lk * 8]);
        // O += P @ V ; l-sum via ones column
#pragma unroll
        for (int t = 0; t < 16; ++t) {
            short8 vf = *reinterpret_cast<const short8*>(Hvt + (size_t)(t * 16 + lr) * NN + kb + lk * 8);
            o[t] = __builtin_amdgcn_mfma_f32_16x16x32_bf16(pa, vf, o[t], 0, 0, 0);
        }
        o[16] = __builtin_amdgcn_mfma_f32_16x16x32_bf16(pa, ones, o[16], 0, 0, 0);
    }

    // ---- block-level flash merge of 4 key-split partials ----
    if (lr == 0) {
#pragma unroll
        for (int j = 0; j < 4; ++j) { Msh[w][lk * 4 + j] = m[j]; Lsh[w][lk * 4 + j] = o[16][j]; }
    }
    __syncthreads();
    float fac[4];
#pragma unroll
    for (int j = 0; j < 4; ++j) {
        int q = lk * 4 + j;
        float M = fmaxf(fmaxf(Msh[0][q], Msh[1][q]), fmaxf(Msh[2][q], Msh[3][q]));
        fac[j] = __expf(m[j] - M);
    }
    if (threadIdx.x < 16) {
        int q = threadIdx.x;
        float M = fmaxf(fmaxf(Msh[0][q], Msh[1][q]), fmaxf(Msh[2][q], Msh[3][q]));
        float L = 0.f;
        for (int ww = 0; ww < 4; ++ww) L += __expf(Msh[ww][q] - M) * Lsh[ww][q];
        Lrow[q] = L;
    }
    for (int ww = 0; ww < 4; ++ww) {
        if (w == ww) {
#pragma unroll
            for (int t = 0; t < 16; ++t)
#pragma unroll
                for (int j = 0; j < 4; ++j)
                    Osum[lk * 4 + j][t * 16 + lr] += fac[j] * o[t][j];
        }
        __syncthreads();
    }
    // final: H = (ALPHA*Q + Osum/L) / (ALPHA+BETA); emit f32 and/or bf16+bf16^T
    for (int rep = 0; rep < 16; ++rep) {
        int cc = threadIdx.x;
        float val = (ALPHA * Qo[(size_t)(q0 + rep) * DD + cc] + Osum[rep][cc] / Lrow[rep])
                    * (1.0f / (ALPHA + BETA));
        Osum[rep][cc] = val;
        if (Fout)  Fout[(size_t)(q0 + rep) * DD + cc] = val;
        if (HvOut) HvOut[(size_t)(q0 + rep) * DD + cc] = f2bf(val);
    }
    __syncthreads();
    if (HvtOut) {
#pragma unroll
        for (int p = 0; p < 16; ++p) {
            int cc = p * 16 + (threadIdx.x >> 4);
            int r  = threadIdx.x & 15;
            HvtOut[(size_t)cc * NN + q0 + r] = f2bf(Osum[r][cc]);
        }
    }
}

extern "C" void kernel_launch(void* const* d_in, const int* in_sizes, int n_in,
                              void* d_out, int out_size, void* d_ws, size_t ws_size,
                              hipStream_t stream) {
    const float* Q   = (const float*)d_in[0];
    const float* sim = (const float*)d_in[1];
    const float* W   = (const float*)d_in[2];
    const float* b   = (const float*)d_in[3];
    float* out = (float*)d_out;

    char* ws = (char*)d_ws;
    size_t off = 0;
    ushort* Hv   = (ushort*)(ws + off); off += (size_t)NN * DD * 2;
    ushort* HvtA = (ushort*)(ws + off); off += (size_t)NN * DD * 2;
    ushort* HvtB = (ushort*)(ws + off); off += (size_t)NN * DD * 2;
    ushort* Hp   = (ushort*)(ws + off); off += (size_t)NN * DD * 2;
    ushort* Wb   = (ushort*)(ws + off); off += (size_t)DD * DD * 2;
    unsigned* bits = (unsigned*)(ws + off); off += (size_t)NN * (NN / 32) * 4;

    k_wconv<<<DD * DD / 256, 256, 0, stream>>>(W, Wb);
    k_pack<<<NN, 256, 0, stream>>>(sim, bits);
    k_convert<<<(NN / 64) * (DD / 64), 256, 0, stream>>>(Q, Hv, HvtA);

    // iter 1: V = Q (HvtA); emit bf16 H (Hv) + transposed (HvtB)
    k_proj<<<NN / 64, 256, 0, stream>>>(Hv, Wb, b, Hp);
    k_attn<<<NN / 16, 256, 0, stream>>>(Hp, HvtA, bits, Q, Hv, HvtB, nullptr);

    // iter 2: V = H1 (HvtB); emit f32 out
    k_proj<<<NN / 64, 256, 0, stream>>>(Hv, Wb, b, Hp);
    k_attn<<<NN / 16, 256, 0, stream>>>(Hp, HvtB, bits, Q, nullptr, nullptr, out);
}